// Round 1
// baseline (343.709 us; speedup 1.0000x reference)
//
#include <hip/hip_runtime.h>
#include <math.h>

// FastFood layer: out = (1/sqrt(D)) * [cos(w), sin(w)] + bias
//   w = (1/sqrt(D)) * S ⊙ FWHT( G ⊙ Perm( FWHT( B ⊙ x ) ) )
// Dense Hadamard matmuls in the reference are replaced by fast
// Walsh-Hadamard transforms (stages commute: tensor-product structure).
//
// Layout: 1 block = 1 row, 256 threads, 4 elements/thread (D=1024).
//   element index e bits [5:0] = lane, [7:6] = (thread>>6 after remap),
//   FWHT strides 1..32  -> __shfl_xor within wave
//   FWHT strides 256,512-> register-local butterflies (k bits 8,9)
//   FWHT strides 64,128 -> one LDS round-trip remap (bits 6,7 -> regs)

#define FF_D 1024
#define FF_STACK 4
#define FF_NT 256

__device__ __forceinline__ void bf_pair(float& a, float& b) {
    float s = a + b;
    float d = a - b;
    a = s; b = d;
}

__global__ __launch_bounds__(FF_NT) void fastfood_kernel(
    const float* __restrict__ x,
    const float* __restrict__ Bsign,
    const float* __restrict__ G,
    const float* __restrict__ S,
    const float* __restrict__ bias,
    const int* __restrict__ P,
    float* __restrict__ out)
{
    __shared__ float lds[FF_D];
    const int row  = blockIdx.x;
    const int t    = threadIdx.x;
    const int lane = t & 63;
    const int wave = t >> 6;

    // Load x row once: elements t + 256k (coalesced dword loads).
    float xr[4];
    #pragma unroll
    for (int k = 0; k < 4; ++k) xr[k] = x[row * FF_D + t + FF_NT * k];

    const float inv_sqrt_d = 0.03125f; // 1/sqrt(1024), sigma = 1

    for (int s = 0; s < FF_STACK; ++s) {
        float v[4];
        #pragma unroll
        for (int k = 0; k < 4; ++k)
            v[k] = xr[k] * Bsign[s * FF_D + t + FF_NT * k];

        // ---------------- FWHT #1 ----------------
        // strides 1..32 via cross-lane shuffle (element bits 0..5 == lane)
        #pragma unroll
        for (int st = 1; st <= 32; st <<= 1) {
            #pragma unroll
            for (int k = 0; k < 4; ++k) {
                float p = __shfl_xor(v[k], st, 64);
                v[k] = (lane & st) ? (p - v[k]) : (v[k] + p);
            }
        }
        // strides 256, 512 (k bits) in registers
        bf_pair(v[0], v[1]); bf_pair(v[2], v[3]);  // stride 256
        bf_pair(v[0], v[2]); bf_pair(v[1], v[3]);  // stride 512
        // strides 64, 128 need a cross-wave remap through LDS
        __syncthreads();                       // prior pass's reads complete
        #pragma unroll
        for (int k = 0; k < 4; ++k) lds[t + FF_NT * k] = v[k];
        __syncthreads();
        #pragma unroll
        for (int k = 0; k < 4; ++k)
            v[k] = lds[lane + 64 * k + 256 * wave];  // now k = bits 6,7
        bf_pair(v[0], v[1]); bf_pair(v[2], v[3]);  // stride 64
        bf_pair(v[0], v[2]); bf_pair(v[1], v[3]);  // stride 128
        // stash full transform result for the permutation gather
        __syncthreads();
        #pragma unroll
        for (int k = 0; k < 4; ++k) lds[lane + 64 * k + 256 * wave] = v[k];
        __syncthreads();

        // ---------------- permutation gather + diag G ----------------
        // P entries for stack s lie in [s*D, (s+1)*D): local index = P & (D-1)
        #pragma unroll
        for (int k = 0; k < 4; ++k) {
            int j = s * FF_D + t + FF_NT * k;
            v[k] = lds[P[j] & (FF_D - 1)] * G[j];
        }

        // ---------------- FWHT #2 ----------------
        #pragma unroll
        for (int st = 1; st <= 32; st <<= 1) {
            #pragma unroll
            for (int k = 0; k < 4; ++k) {
                float p = __shfl_xor(v[k], st, 64);
                v[k] = (lane & st) ? (p - v[k]) : (v[k] + p);
            }
        }
        bf_pair(v[0], v[1]); bf_pair(v[2], v[3]);  // stride 256
        bf_pair(v[0], v[2]); bf_pair(v[1], v[3]);  // stride 512
        __syncthreads();                       // gather reads complete
        #pragma unroll
        for (int k = 0; k < 4; ++k) lds[t + FF_NT * k] = v[k];
        __syncthreads();
        #pragma unroll
        for (int k = 0; k < 4; ++k)
            v[k] = lds[lane + 64 * k + 256 * wave];
        bf_pair(v[0], v[1]); bf_pair(v[2], v[3]);  // stride 64
        bf_pair(v[0], v[2]); bf_pair(v[1], v[3]);  // stride 128

        // ---------------- epilogue: scale, sincos, store ----------------
        #pragma unroll
        for (int k = 0; k < 4; ++k) {
            int e = lane + 64 * k + 256 * wave;  // true element index
            int j = s * FF_D + e;
            float w = v[k] * inv_sqrt_d * S[j];
            float sn, cs;
            __sincosf(w, &sn, &cs);
            long long base = (long long)row * (2 * FF_STACK * FF_D);
            out[base + j] = cs * inv_sqrt_d + bias[j];
            out[base + FF_STACK * FF_D + j] =
                sn * inv_sqrt_d + bias[FF_STACK * FF_D + j];
        }
    }
}

extern "C" void kernel_launch(void* const* d_in, const int* in_sizes, int n_in,
                              void* d_out, int out_size, void* d_ws, size_t ws_size,
                              hipStream_t stream) {
    // setup_inputs order: x, B, G, S, bias, H, P   (H unused: FWHT instead)
    const float* x    = (const float*)d_in[0];
    const float* B    = (const float*)d_in[1];
    const float* G    = (const float*)d_in[2];
    const float* S    = (const float*)d_in[3];
    const float* bias = (const float*)d_in[4];
    const int*   P    = (const int*)d_in[6];
    float* out = (float*)d_out;

    const int n_rows = in_sizes[0] / FF_D;  // 8192
    fastfood_kernel<<<n_rows, FF_NT, 0, stream>>>(x, B, G, S, bias, P, out);
}

// Round 2
// 326.034 us; speedup vs baseline: 1.0542x; 1.0542x over previous
//
#include <hip/hip_runtime.h>
#include <math.h>

// FastFood layer: out = (1/sqrt(D)) * [cos(w), sin(w)] + bias
//   w = (1/sqrt(D)) * S ⊙ FWHT( G ⊙ Perm( FWHT( B ⊙ x ) ) )
//
// Wave-per-row design (D=1024, 16 elems/lane, wave-private LDS, no
// __syncthreads). FWHT element-index bit mappings onto (lane, reg):
//   A: regs r[1:0]=e[1:0], r[3:2]=e[9:8]; lanes = e[7:2]   (strides 1,2,256,512)
//   B: regs r[3:0]=e[5:2]; lanes = e[1:0],e[9:6]           (strides 4..32)
//   C: regs r[1:0]=e[1:0], r[3:2]=e[7:6]; lanes = e[5:2],e[9:8] (strides 64,128)
// All butterflies are register add/sub; remaps go through LDS with an XOR
// swizzle idx = e ^ (e[8:6]<<2) -> every pattern <=2-way conflict (free),
// float4 groups (bits 1:0) stay contiguous & 16B-aligned.

#define FF_D 1024
#define FF_STACK 4
#define FF_NT 256
#define ROWS_PER_BLOCK 4

__device__ __forceinline__ int swz(int e) { return e ^ (((e >> 6) & 7) << 2); }

#define STAGE_BIT(vv, m) { \
    _Pragma("unroll") \
    for (int i_ = 0; i_ < 16; ++i_) \
        if (!(i_ & (m))) { \
            float s_ = vv[i_] + vv[i_ | (m)]; \
            float d_ = vv[i_] - vv[i_ | (m)]; \
            vv[i_] = s_; vv[i_ | (m)] = d_; \
        } \
}

__global__ __launch_bounds__(FF_NT) void fastfood_kernel(
    const float* __restrict__ x,
    const float* __restrict__ Bs,
    const float* __restrict__ G,
    const float* __restrict__ S,
    const float* __restrict__ bias,
    const int*   __restrict__ P,
    float* __restrict__ out)
{
    __shared__ float lds[ROWS_PER_BLOCK * FF_D];
    const int lane = threadIdx.x & 63;
    const int wave = threadIdx.x >> 6;
    const int row  = blockIdx.x * ROWS_PER_BLOCK + wave;
    float* wl = lds + (wave << 10);

    // A-mapping: element group base (q<<8)|(lane<<2), 4 consecutive elems
    float xr[16];
    #pragma unroll
    for (int q = 0; q < 4; ++q) {
        const float4 t = *(const float4*)&x[((long long)row << 10) + (q << 8) + (lane << 2)];
        xr[4*q+0] = t.x; xr[4*q+1] = t.y; xr[4*q+2] = t.z; xr[4*q+3] = t.w;
    }

    const int eB = (lane & 3) | ((lane & 60) << 4);   // B-mapping lane base
    const float kout = 0.03125f;                      // 1/sqrt(1024)
    const float karg = 0.03125f * 0.15915494309f;     // 1/(sqrt(D)*2*pi): revolutions

    for (int s = 0; s < FF_STACK; ++s) {
        const int sb = s << 10;
        float v[16];

        // diag B (A mapping)
        #pragma unroll
        for (int q = 0; q < 4; ++q) {
            const float4 b4 = *(const float4*)&Bs[sb + (q << 8) + (lane << 2)];
            v[4*q+0] = xr[4*q+0] * b4.x; v[4*q+1] = xr[4*q+1] * b4.y;
            v[4*q+2] = xr[4*q+2] * b4.z; v[4*q+3] = xr[4*q+3] * b4.w;
        }

        // ---------- FWHT #1 ----------
        STAGE_BIT(v, 1) STAGE_BIT(v, 2) STAGE_BIT(v, 4) STAGE_BIT(v, 8)   // e bits 0,1,8,9
        // remap A -> B
        #pragma unroll
        for (int q = 0; q < 4; ++q)
            *(float4*)&wl[swz((q << 8) | (lane << 2))] =
                make_float4(v[4*q], v[4*q+1], v[4*q+2], v[4*q+3]);
        __builtin_amdgcn_wave_barrier();
        #pragma unroll
        for (int r = 0; r < 16; ++r) v[r] = wl[swz(eB | (r << 2))];
        STAGE_BIT(v, 1) STAGE_BIT(v, 2) STAGE_BIT(v, 4) STAGE_BIT(v, 8)   // e bits 2..5
        // remap B -> C
        __builtin_amdgcn_wave_barrier();
        #pragma unroll
        for (int r = 0; r < 16; ++r) wl[swz(eB | (r << 2))] = v[r];
        __builtin_amdgcn_wave_barrier();
        #pragma unroll
        for (int q = 0; q < 4; ++q) {
            const float4 t = *(const float4*)&wl[swz(((lane & 15) << 2) | (q << 6) | ((lane & 48) << 4))];
            v[4*q+0] = t.x; v[4*q+1] = t.y; v[4*q+2] = t.z; v[4*q+3] = t.w;
        }
        STAGE_BIT(v, 4) STAGE_BIT(v, 8)                                   // e bits 6,7

        // ---------- permutation gather + diag G (into A mapping) ----------
        __builtin_amdgcn_wave_barrier();
        #pragma unroll
        for (int q = 0; q < 4; ++q)
            *(float4*)&wl[swz(((lane & 15) << 2) | (q << 6) | ((lane & 48) << 4))] =
                make_float4(v[4*q], v[4*q+1], v[4*q+2], v[4*q+3]);
        __builtin_amdgcn_wave_barrier();
        #pragma unroll
        for (int q = 0; q < 4; ++q) {
            const int jb = sb + (q << 8) + (lane << 2);
            const int4   p4 = *(const int4*)&P[jb];
            const float4 g4 = *(const float4*)&G[jb];
            v[4*q+0] = wl[swz(p4.x & (FF_D - 1))] * g4.x;
            v[4*q+1] = wl[swz(p4.y & (FF_D - 1))] * g4.y;
            v[4*q+2] = wl[swz(p4.z & (FF_D - 1))] * g4.z;
            v[4*q+3] = wl[swz(p4.w & (FF_D - 1))] * g4.w;
        }

        // ---------- FWHT #2 ----------
        STAGE_BIT(v, 1) STAGE_BIT(v, 2) STAGE_BIT(v, 4) STAGE_BIT(v, 8)   // e bits 0,1,8,9
        __builtin_amdgcn_wave_barrier();
        #pragma unroll
        for (int q = 0; q < 4; ++q)
            *(float4*)&wl[swz((q << 8) | (lane << 2))] =
                make_float4(v[4*q], v[4*q+1], v[4*q+2], v[4*q+3]);
        __builtin_amdgcn_wave_barrier();
        #pragma unroll
        for (int r = 0; r < 16; ++r) v[r] = wl[swz(eB | (r << 2))];
        STAGE_BIT(v, 1) STAGE_BIT(v, 2) STAGE_BIT(v, 4) STAGE_BIT(v, 8)   // e bits 2..5
        __builtin_amdgcn_wave_barrier();
        #pragma unroll
        for (int r = 0; r < 16; ++r) wl[swz(eB | (r << 2))] = v[r];
        __builtin_amdgcn_wave_barrier();
        #pragma unroll
        for (int q = 0; q < 4; ++q) {
            const float4 t = *(const float4*)&wl[swz(((lane & 15) << 2) | (q << 6) | ((lane & 48) << 4))];
            v[4*q+0] = t.x; v[4*q+1] = t.y; v[4*q+2] = t.z; v[4*q+3] = t.w;
        }
        STAGE_BIT(v, 4) STAGE_BIT(v, 8)                                   // e bits 6,7

        // ---------- epilogue (C mapping): scale, sincos, store ----------
        const long long obase = ((long long)row << 13);   // row * 8192
        #pragma unroll
        for (int q = 0; q < 4; ++q) {
            const int e0 = ((lane & 15) << 2) | (q << 6) | ((lane & 48) << 4);
            const int j  = sb + e0;
            const float4 s4  = *(const float4*)&S[j];
            const float4 bc4 = *(const float4*)&bias[j];
            const float4 bs4 = *(const float4*)&bias[FF_STACK * FF_D + j];
            float4 oc, os;
            {
                const float tr = __builtin_amdgcn_fractf(v[4*q+0] * (s4.x * karg));
                oc.x = __builtin_amdgcn_cosf(tr) * kout + bc4.x;
                os.x = __builtin_amdgcn_sinf(tr) * kout + bs4.x;
            }
            {
                const float tr = __builtin_amdgcn_fractf(v[4*q+1] * (s4.y * karg));
                oc.y = __builtin_amdgcn_cosf(tr) * kout + bc4.y;
                os.y = __builtin_amdgcn_sinf(tr) * kout + bs4.y;
            }
            {
                const float tr = __builtin_amdgcn_fractf(v[4*q+2] * (s4.z * karg));
                oc.z = __builtin_amdgcn_cosf(tr) * kout + bc4.z;
                os.z = __builtin_amdgcn_sinf(tr) * kout + bs4.z;
            }
            {
                const float tr = __builtin_amdgcn_fractf(v[4*q+3] * (s4.w * karg));
                oc.w = __builtin_amdgcn_cosf(tr) * kout + bc4.w;
                os.w = __builtin_amdgcn_sinf(tr) * kout + bs4.w;
            }
            *(float4*)&out[obase + j] = oc;
            *(float4*)&out[obase + FF_STACK * FF_D + j] = os;
        }
    }
}

extern "C" void kernel_launch(void* const* d_in, const int* in_sizes, int n_in,
                              void* d_out, int out_size, void* d_ws, size_t ws_size,
                              hipStream_t stream) {
    // setup_inputs order: x, B, G, S, bias, H, P   (H unused: FWHT instead)
    const float* x    = (const float*)d_in[0];
    const float* B    = (const float*)d_in[1];
    const float* G    = (const float*)d_in[2];
    const float* S    = (const float*)d_in[3];
    const float* bias = (const float*)d_in[4];
    const int*   P    = (const int*)d_in[6];
    float* out = (float*)d_out;

    const int n_rows = in_sizes[0] / FF_D;                 // 8192
    const int blocks = n_rows / ROWS_PER_BLOCK;            // 2048
    fastfood_kernel<<<blocks, FF_NT, 0, stream>>>(x, B, G, S, bias, P, out);
}

// Round 3
// 323.351 us; speedup vs baseline: 1.0630x; 1.0083x over previous
//
#include <hip/hip_runtime.h>
#include <math.h>

// FastFood layer: out = (1/sqrt(D)) * [cos(w), sin(w)] + bias
//   w = (1/sqrt(D)) * S ⊙ FWHT( G ⊙ Perm( FWHT( B ⊙ x ) ) )
//
// Stack-per-wave design: block = 1 row (256 thr), wave w = stack w.
// The 4 stacks are independent -> wave critical path is 1 stack (was 4),
// 4x less exposed LDS-remap latency per wave, 8192 blocks.
//
// FWHT element-index bit mappings onto (lane, reg):
//   A: regs r[1:0]=e[1:0], r[3:2]=e[9:8]; lanes = e[7:2]   (strides 1,2,256,512)
//   B: regs r[3:0]=e[5:2]; lanes = e[1:0],e[9:6]           (strides 4..32)
//   C: regs r[1:0]=e[1:0], r[3:2]=e[7:6]; lanes = e[5:2],e[9:8] (strides 64,128)
// All butterflies are register add/sub; remaps go through wave-private LDS
// with an XOR swizzle idx = e ^ (e[8:6]<<2) -> every pattern <=2-way bank
// conflict (free), float4 groups (bits 1:0) stay contiguous & 16B-aligned.

#define FF_D 1024
#define FF_STACK 4
#define FF_NT 256

__device__ __forceinline__ int swz(int e) { return e ^ (((e >> 6) & 7) << 2); }

#define STAGE_BIT(vv, m) { \
    _Pragma("unroll") \
    for (int i_ = 0; i_ < 16; ++i_) \
        if (!(i_ & (m))) { \
            float s_ = vv[i_] + vv[i_ | (m)]; \
            float d_ = vv[i_] - vv[i_ | (m)]; \
            vv[i_] = s_; vv[i_ | (m)] = d_; \
        } \
}

__global__ __launch_bounds__(FF_NT) void fastfood_kernel(
    const float* __restrict__ x,
    const float* __restrict__ Bs,
    const float* __restrict__ G,
    const float* __restrict__ S,
    const float* __restrict__ bias,
    const int*   __restrict__ P,
    float* __restrict__ out)
{
    __shared__ float lds[FF_STACK * FF_D];
    const int lane = threadIdx.x & 63;
    const int s    = threadIdx.x >> 6;      // stack handled by this wave
    const int row  = blockIdx.x;
    const int sb   = s << 10;
    float* wl = lds + sb;                   // wave-private 4 KB

    const int eB = (lane & 3) | ((lane & 60) << 4);   // B-mapping lane base
    const float kout = 0.03125f;                      // 1/sqrt(1024)
    const float karg = 0.03125f * 0.15915494309f;     // /(2*pi): revolutions

    float v[16];

    // Load x row (A mapping), fused with diag B.
    #pragma unroll
    for (int q = 0; q < 4; ++q) {
        const float4 t  = *(const float4*)&x[((long long)row << 10) + (q << 8) + (lane << 2)];
        const float4 b4 = *(const float4*)&Bs[sb + (q << 8) + (lane << 2)];
        v[4*q+0] = t.x * b4.x; v[4*q+1] = t.y * b4.y;
        v[4*q+2] = t.z * b4.z; v[4*q+3] = t.w * b4.w;
    }

    // ---------- FWHT #1 ----------
    STAGE_BIT(v, 1) STAGE_BIT(v, 2) STAGE_BIT(v, 4) STAGE_BIT(v, 8)   // e bits 0,1,8,9
    // remap A -> B
    #pragma unroll
    for (int q = 0; q < 4; ++q)
        *(float4*)&wl[swz((q << 8) | (lane << 2))] =
            make_float4(v[4*q], v[4*q+1], v[4*q+2], v[4*q+3]);
    __builtin_amdgcn_wave_barrier();
    #pragma unroll
    for (int r = 0; r < 16; ++r) v[r] = wl[swz(eB | (r << 2))];
    STAGE_BIT(v, 1) STAGE_BIT(v, 2) STAGE_BIT(v, 4) STAGE_BIT(v, 8)   // e bits 2..5
    // remap B -> C
    __builtin_amdgcn_wave_barrier();
    #pragma unroll
    for (int r = 0; r < 16; ++r) wl[swz(eB | (r << 2))] = v[r];
    __builtin_amdgcn_wave_barrier();
    #pragma unroll
    for (int q = 0; q < 4; ++q) {
        const float4 t = *(const float4*)&wl[swz(((lane & 15) << 2) | (q << 6) | ((lane & 48) << 4))];
        v[4*q+0] = t.x; v[4*q+1] = t.y; v[4*q+2] = t.z; v[4*q+3] = t.w;
    }
    STAGE_BIT(v, 4) STAGE_BIT(v, 8)                                   // e bits 6,7

    // ---------- permutation gather + diag G (into A mapping) ----------
    __builtin_amdgcn_wave_barrier();
    #pragma unroll
    for (int q = 0; q < 4; ++q)
        *(float4*)&wl[swz(((lane & 15) << 2) | (q << 6) | ((lane & 48) << 4))] =
            make_float4(v[4*q], v[4*q+1], v[4*q+2], v[4*q+3]);
    __builtin_amdgcn_wave_barrier();
    #pragma unroll
    for (int q = 0; q < 4; ++q) {
        const int jb = sb + (q << 8) + (lane << 2);
        const int4   p4 = *(const int4*)&P[jb];
        const float4 g4 = *(const float4*)&G[jb];
        v[4*q+0] = wl[swz(p4.x & (FF_D - 1))] * g4.x;
        v[4*q+1] = wl[swz(p4.y & (FF_D - 1))] * g4.y;
        v[4*q+2] = wl[swz(p4.z & (FF_D - 1))] * g4.z;
        v[4*q+3] = wl[swz(p4.w & (FF_D - 1))] * g4.w;
    }

    // ---------- FWHT #2 ----------
    STAGE_BIT(v, 1) STAGE_BIT(v, 2) STAGE_BIT(v, 4) STAGE_BIT(v, 8)   // e bits 0,1,8,9
    __builtin_amdgcn_wave_barrier();
    #pragma unroll
    for (int q = 0; q < 4; ++q)
        *(float4*)&wl[swz((q << 8) | (lane << 2))] =
            make_float4(v[4*q], v[4*q+1], v[4*q+2], v[4*q+3]);
    __builtin_amdgcn_wave_barrier();
    #pragma unroll
    for (int r = 0; r < 16; ++r) v[r] = wl[swz(eB | (r << 2))];
    STAGE_BIT(v, 1) STAGE_BIT(v, 2) STAGE_BIT(v, 4) STAGE_BIT(v, 8)   // e bits 2..5
    __builtin_amdgcn_wave_barrier();
    #pragma unroll
    for (int r = 0; r < 16; ++r) wl[swz(eB | (r << 2))] = v[r];
    __builtin_amdgcn_wave_barrier();
    #pragma unroll
    for (int q = 0; q < 4; ++q) {
        const float4 t = *(const float4*)&wl[swz(((lane & 15) << 2) | (q << 6) | ((lane & 48) << 4))];
        v[4*q+0] = t.x; v[4*q+1] = t.y; v[4*q+2] = t.z; v[4*q+3] = t.w;
    }
    STAGE_BIT(v, 4) STAGE_BIT(v, 8)                                   // e bits 6,7

    // ---------- epilogue (C mapping): scale, sincos, store ----------
    const long long obase = ((long long)row << 13);   // row * 8192
    #pragma unroll
    for (int q = 0; q < 4; ++q) {
        const int e0 = ((lane & 15) << 2) | (q << 6) | ((lane & 48) << 4);
        const int j  = sb + e0;
        const float4 s4  = *(const float4*)&S[j];
        const float4 bc4 = *(const float4*)&bias[j];
        const float4 bs4 = *(const float4*)&bias[FF_STACK * FF_D + j];
        float4 oc, os;
        {
            const float tr = __builtin_amdgcn_fractf(v[4*q+0] * (s4.x * karg));
            oc.x = __builtin_amdgcn_cosf(tr) * kout + bc4.x;
            os.x = __builtin_amdgcn_sinf(tr) * kout + bs4.x;
        }
        {
            const float tr = __builtin_amdgcn_fractf(v[4*q+1] * (s4.y * karg));
            oc.y = __builtin_amdgcn_cosf(tr) * kout + bc4.y;
            os.y = __builtin_amdgcn_sinf(tr) * kout + bs4.y;
        }
        {
            const float tr = __builtin_amdgcn_fractf(v[4*q+2] * (s4.z * karg));
            oc.z = __builtin_amdgcn_cosf(tr) * kout + bc4.z;
            os.z = __builtin_amdgcn_sinf(tr) * kout + bs4.z;
        }
        {
            const float tr = __builtin_amdgcn_fractf(v[4*q+3] * (s4.w * karg));
            oc.w = __builtin_amdgcn_cosf(tr) * kout + bc4.w;
            os.w = __builtin_amdgcn_sinf(tr) * kout + bs4.w;
        }
        *(float4*)&out[obase + j] = oc;
        *(float4*)&out[obase + FF_STACK * FF_D + j] = os;
    }
}

extern "C" void kernel_launch(void* const* d_in, const int* in_sizes, int n_in,
                              void* d_out, int out_size, void* d_ws, size_t ws_size,
                              hipStream_t stream) {
    // setup_inputs order: x, B, G, S, bias, H, P   (H unused: FWHT instead)
    const float* x    = (const float*)d_in[0];
    const float* B    = (const float*)d_in[1];
    const float* G    = (const float*)d_in[2];
    const float* S    = (const float*)d_in[3];
    const float* bias = (const float*)d_in[4];
    const int*   P    = (const int*)d_in[6];
    float* out = (float*)d_out;

    const int n_rows = in_sizes[0] / FF_D;   // 8192
    fastfood_kernel<<<n_rows, FF_NT, 0, stream>>>(x, B, G, S, bias, P, out);
}